// Round 2
// baseline (965.690 us; speedup 1.0000x reference)
//
#include <hip/hip_runtime.h>

// ---------------- prep: transpose W[r][d][e] -> Wt[r][e][d] ----------------

__global__ __launch_bounds__(256) void wt_kernel(
    const float* __restrict__ W, float* __restrict__ Wt) {
  int idx = blockIdx.x * 256 + threadIdx.x;
  if (idx < 3 * 64 * 64) {
    int r = idx >> 12, rem = idx & 4095, d = rem >> 6, e = rem & 63;
    Wt[(r << 12) + (e << 6) + d] = W[idx];
  }
}

// ---------------- CSR build ----------------

__global__ __launch_bounds__(256) void count_kernel(
    const int* __restrict__ dst, unsigned* __restrict__ counts, int E) {
  int e = blockIdx.x * 256 + threadIdx.x;
  if (e < E) atomicAdd(&counts[dst[e]], 1u);
}

__global__ __launch_bounds__(1024) void scan_k1(
    const unsigned* __restrict__ counts, unsigned* __restrict__ offs,
    unsigned* __restrict__ bsums, int N) {
  __shared__ unsigned sm[1024];
  int tid = threadIdx.x;
  int i = blockIdx.x * 1024 + tid;
  unsigned v = (i < N) ? counts[i] : 0u;
  sm[tid] = v;
  __syncthreads();
  for (int ofs = 1; ofs < 1024; ofs <<= 1) {
    unsigned add = (tid >= ofs) ? sm[tid - ofs] : 0u;
    __syncthreads();
    sm[tid] += add;
    __syncthreads();
  }
  if (i < N) offs[i] = sm[tid] - v;
  if (tid == 0) bsums[blockIdx.x] = sm[1023];
}

__global__ __launch_bounds__(128) void scan_k2(
    unsigned* __restrict__ bsums, unsigned* __restrict__ offs, int M, int N) {
  __shared__ unsigned sm[128];
  int tid = threadIdx.x;
  unsigned v = (tid < M) ? bsums[tid] : 0u;
  sm[tid] = v;
  __syncthreads();
  for (int ofs = 1; ofs < 128; ofs <<= 1) {
    unsigned add = (tid >= ofs) ? sm[tid - ofs] : 0u;
    __syncthreads();
    sm[tid] += add;
    __syncthreads();
  }
  if (tid < M) bsums[tid] = sm[tid] - v;
  if (tid == 127) offs[N] = sm[127];
}

__global__ __launch_bounds__(256) void scan_k3(
    unsigned* __restrict__ offs, const unsigned* __restrict__ bsums,
    unsigned* __restrict__ cursor, int N) {
  int i = blockIdx.x * 256 + threadIdx.x;
  if (i < N) {
    unsigned o = offs[i] + bsums[i >> 10];
    offs[i] = o;
    cursor[i] = o;
  }
}

__global__ __launch_bounds__(256) void fill_kernel(
    const int* __restrict__ src, const int* __restrict__ dst,
    const int* __restrict__ rel, const float* __restrict__ norm,
    unsigned* __restrict__ cursor, unsigned* __restrict__ packed,
    float* __restrict__ norms, int E) {
  int e = blockIdx.x * 256 + threadIdx.x;
  if (e < E) {
    int d = dst[e];
    unsigned p = atomicAdd(&cursor[d], 1u);
    packed[p] = (unsigned)src[e] | ((unsigned)rel[e] << 20);
    norms[p] = norm[e];
  }
}

// ---------------- transform: t[r][n][e] = sum_d x[n][d] * W[r][d][e] ----------------
// node-per-lane; weights via wave-uniform s_load of Wt rows; LDS-transposed stores.

__global__ __launch_bounds__(192) void transform_kernel(
    const float* __restrict__ x, const float* __restrict__ Wt,
    float* __restrict__ t, int N) {
  __shared__ float tile[3][16][68];
  int tid = threadIdx.x;
  int w = __builtin_amdgcn_readfirstlane(tid >> 6);  // rel index 0..2
  int lane = tid & 63;
  int n0 = blockIdx.x * 64;
  int n = n0 + lane;

  float x_[64];
  if (n < N) {
    const float4* xr = (const float4*)(x + (size_t)n * 64);
#pragma unroll
    for (int i = 0; i < 16; ++i) {
      float4 v = xr[i];
      x_[4 * i] = v.x; x_[4 * i + 1] = v.y; x_[4 * i + 2] = v.z; x_[4 * i + 3] = v.w;
    }
  } else {
#pragma unroll
    for (int i = 0; i < 64; ++i) x_[i] = 0.f;
  }

  const float* wr = Wt + (size_t)w * 4096;
  float* tbase = t + ((size_t)w * N + n0) * 64;
  int node16 = lane >> 2, q = lane & 3;

  for (int cc = 0; cc < 4; ++cc) {
#pragma unroll 4
    for (int e16 = 0; e16 < 16; ++e16) {
      const float* we = wr + (cc * 16 + e16) * 64;  // uniform -> s_load
      float acc = 0.f;
#pragma unroll
      for (int d = 0; d < 64; ++d) acc = fmaf(x_[d], we[d], acc);
      tile[w][e16][lane] = acc;
    }
    // same-wave LDS dep; compiler inserts lgkmcnt waits
#pragma unroll
    for (int g = 0; g < 4; ++g) {
      int node = g * 16 + node16;
      float4 v;
      v.x = tile[w][4 * q + 0][node];
      v.y = tile[w][4 * q + 1][node];
      v.z = tile[w][4 * q + 2][node];
      v.w = tile[w][4 * q + 3][node];
      if (n0 + node < N)
        *(float4*)(tbase + (size_t)node * 64 + cc * 16 + 4 * q) = v;
    }
  }
}

// ---------------- gather: swh[n][c] = sum_{e: dst=n} t[rel][src][c]*norm ----------------

__global__ __launch_bounds__(256) void gather_kernel(
    const float* __restrict__ t, const unsigned* __restrict__ offs,
    const unsigned* __restrict__ packed, const float* __restrict__ norms,
    float* __restrict__ swh, int N) {
  int lane = threadIdx.x & 63;
  int n = __builtin_amdgcn_readfirstlane(blockIdx.x * 4 + (threadIdx.x >> 6));
  if (n >= N) return;
  unsigned a = offs[n], b = offs[n + 1];
  float acc = 0.f;
  for (unsigned j = a; j < b; ++j) {
    unsigned p = packed[j];   // uniform -> s_load
    float nv = norms[j];      // uniform -> s_load
    int srcn = (int)(p & 0xFFFFFu);
    int r = (int)(p >> 20);
    acc = fmaf(t[((size_t)r * N + srcn) * 64 + lane], nv, acc);
  }
  swh[(size_t)n * 64 + lane] = acc;
}

// ---------------- fused GRU cell (node-per-lane, 4 c-chunks/block) ----------------
// In-place safe: blocks own disjoint node rows; all h reads precede the
// post-__syncthreads stores.

template <int USE_H>
__global__ __launch_bounds__(256) void gru_kernel(
    const float* __restrict__ xin, const float* __restrict__ hin,
    const float* __restrict__ w_ih, const float* __restrict__ w_hh,
    const float* __restrict__ b_ih, const float* __restrict__ b_hh,
    float* __restrict__ hout, int N) {
  __shared__ float tile[64][65];
  int tid = threadIdx.x;
  int w = __builtin_amdgcn_readfirstlane(tid >> 6);
  int c0 = w * 16;
  int lane = tid & 63;
  int n0 = blockIdx.x * 64;
  int n = n0 + lane;

  float x_[64], h_[64];
  if (n < N) {
    const float4* xr = (const float4*)(xin + (size_t)n * 64);
#pragma unroll
    for (int i = 0; i < 16; ++i) {
      float4 v = xr[i];
      x_[4 * i] = v.x; x_[4 * i + 1] = v.y; x_[4 * i + 2] = v.z; x_[4 * i + 3] = v.w;
    }
    if (USE_H) {
      const float4* hr = (const float4*)(hin + (size_t)n * 64);
#pragma unroll
      for (int i = 0; i < 16; ++i) {
        float4 v = hr[i];
        h_[4 * i] = v.x; h_[4 * i + 1] = v.y; h_[4 * i + 2] = v.z; h_[4 * i + 3] = v.w;
      }
    }
  } else {
#pragma unroll
    for (int i = 0; i < 64; ++i) { x_[i] = 0.f; h_[i] = 0.f; }
  }

#pragma unroll 2
  for (int ci = 0; ci < 16; ++ci) {
    int c = c0 + ci;
    const float* wir = w_ih + (size_t)c * 64;          // uniform -> s_load
    const float* wiz = w_ih + (size_t)(64 + c) * 64;
    const float* win = w_ih + (size_t)(128 + c) * 64;
    const float* whr = w_hh + (size_t)c * 64;
    const float* whz = w_hh + (size_t)(64 + c) * 64;
    const float* whn = w_hh + (size_t)(128 + c) * 64;
    float air = 0.f, aiz = 0.f, ain = 0.f;
    float ahr = 0.f, ahz = 0.f, ahn = 0.f;
#pragma unroll
    for (int d = 0; d < 64; ++d) {
      air = fmaf(x_[d], wir[d], air);
      aiz = fmaf(x_[d], wiz[d], aiz);
      ain = fmaf(x_[d], win[d], ain);
      if (USE_H) {
        ahr = fmaf(h_[d], whr[d], ahr);
        ahz = fmaf(h_[d], whz[d], ahz);
        ahn = fmaf(h_[d], whn[d], ahn);
      }
    }
    float hprev = (USE_H && n < N) ? hin[(size_t)n * 64 + c] : 0.f;
    float r = 1.f / (1.f + __expf(-(air + b_ih[c] + ahr + b_hh[c])));
    float z = 1.f / (1.f + __expf(-(aiz + b_ih[64 + c] + ahz + b_hh[64 + c])));
    float nn = tanhf(ain + b_ih[128 + c] + r * (ahn + b_hh[128 + c]));
    tile[c][lane] = (1.f - z) * nn + z * hprev;
  }
  __syncthreads();

  int node = tid >> 2, q = tid & 3;
  if (n0 + node < N) {
#pragma unroll
    for (int cg = 0; cg < 4; ++cg) {
      int cb = cg * 16 + 4 * q;
      float4 v;
      v.x = tile[cb + 0][node];
      v.y = tile[cb + 1][node];
      v.z = tile[cb + 2][node];
      v.w = tile[cb + 3][node];
      *(float4*)(hout + (size_t)(n0 + node) * 64 + cb) = v;
    }
  }
}

// ---------------- batchnorm ----------------

__global__ __launch_bounds__(256) void bn_stats_kernel(
    const float* __restrict__ h, float* __restrict__ stats, int N) {
  int tid = threadIdx.x;
  int c = tid & 63;
  float s = 0.f, ss = 0.f;
  for (int n = blockIdx.x * 4 + (tid >> 6); n < N; n += gridDim.x * 4) {
    float v = h[(size_t)n * 64 + c];
    s += v;
    ss += v * v;
  }
  __shared__ float sm[2][256];
  sm[0][tid] = s;
  sm[1][tid] = ss;
  __syncthreads();
  if (tid < 64) {
    s = sm[0][tid] + sm[0][tid + 64] + sm[0][tid + 128] + sm[0][tid + 192];
    ss = sm[1][tid] + sm[1][tid + 64] + sm[1][tid + 128] + sm[1][tid + 192];
    atomicAdd(&stats[tid], s);
    atomicAdd(&stats[64 + tid], ss);
  }
}

__global__ __launch_bounds__(256) void bn_apply_kernel(
    float* out, const float* __restrict__ stats,
    const float* __restrict__ gamma, const float* __restrict__ beta,
    int N, int total) {
  int idx = blockIdx.x * 256 + threadIdx.x;
  if (idx >= total) return;
  int c = idx & 63;
  float invN = 1.f / (float)N;
  float mean = stats[c] * invN;
  float var = stats[64 + c] * invN - mean * mean;
  float sc = rsqrtf(var + 1e-5f) * gamma[c];
  float sh = beta[c] - mean * sc;
  out[idx] = out[idx] * sc + sh;
}

// ---------------- launch ----------------

extern "C" void kernel_launch(void* const* d_in, const int* in_sizes, int n_in,
                              void* d_out, int out_size, void* d_ws, size_t ws_size,
                              hipStream_t stream) {
  const float* h     = (const float*)d_in[0];
  const float* norm  = (const float*)d_in[1];
  const float* W     = (const float*)d_in[2];
  const float* w_ih  = (const float*)d_in[3];
  const float* w_hh  = (const float*)d_in[4];
  const float* b_ih  = (const float*)d_in[5];
  const float* b_hh  = (const float*)d_in[6];
  const float* gamma = (const float*)d_in[7];
  const float* beta  = (const float*)d_in[8];
  const int* src     = (const int*)d_in[9];
  const int* dst     = (const int*)d_in[10];
  const int* rel     = (const int*)d_in[11];
  float* out = (float*)d_out;

  const int N = in_sizes[0] / 64;
  const int E = in_sizes[1];

  char* w = (char*)d_ws;
  float* t = (float*)w;            w += (size_t)3 * N * 64 * 4;
  float* swh = (float*)w;          w += (size_t)N * 64 * 4;
  float* Wt = (float*)w;           w += 3 * 64 * 64 * 4;
  unsigned* offs = (unsigned*)w;   w += ((size_t)N + 4) * 4;
  unsigned* cursor = (unsigned*)w; w += (size_t)N * 4;
  unsigned* packed = (unsigned*)w; w += (size_t)E * 4;
  float* norms = (float*)w;        w += (size_t)E * 4;
  unsigned* bsums = (unsigned*)w;  w += 128 * 4;
  float* stats = (float*)w;        w += 128 * 4;

  const int M = (N + 1023) / 1024;
  const int NB = (N + 63) / 64;

  hipMemsetAsync(cursor, 0, (size_t)N * 4, stream);
  hipMemsetAsync(stats, 0, 128 * 4, stream);

  wt_kernel<<<48, 256, 0, stream>>>(W, Wt);

  // CSR over dst (graph is layer-invariant)
  count_kernel<<<(E + 255) / 256, 256, 0, stream>>>(dst, cursor, E);
  scan_k1<<<M, 1024, 0, stream>>>(cursor, offs, bsums, N);
  scan_k2<<<1, 128, 0, stream>>>(bsums, offs, M, N);
  scan_k3<<<(N + 255) / 256, 256, 0, stream>>>(offs, bsums, cursor, N);
  fill_kernel<<<(E + 255) / 256, 256, 0, stream>>>(src, dst, rel, norm, cursor,
                                                   packed, norms, E);

  // layer 0: hstate = 0
  transform_kernel<<<NB, 192, 0, stream>>>(h, Wt, t, N);
  gather_kernel<<<(N + 3) / 4, 256, 0, stream>>>(t, offs, packed, norms, swh, N);
  gru_kernel<0><<<NB, 256, 0, stream>>>(swh, out, w_ih, w_hh, b_ih, b_hh, out, N);

  // layer 1: hstate = out (in-place safe)
  transform_kernel<<<NB, 192, 0, stream>>>(out, Wt, t, N);
  gather_kernel<<<(N + 3) / 4, 256, 0, stream>>>(t, offs, packed, norms, swh, N);
  gru_kernel<1><<<NB, 256, 0, stream>>>(swh, out, w_ih, w_hh, b_ih, b_hh, out, N);

  bn_stats_kernel<<<256, 256, 0, stream>>>(out, stats, N);
  int total = N * 64;
  bn_apply_kernel<<<(total + 255) / 256, 256, 0, stream>>>(out, stats, gamma,
                                                           beta, N, total);
}

// Round 3
// 544.246 us; speedup vs baseline: 1.7744x; 1.7744x over previous
//
#include <hip/hip_runtime.h>

// ---------------- prep: transpose GRU weights w[k][d] -> wt[d][k] ----------------

__global__ __launch_bounds__(256) void transpose_w_kernel(
    const float* __restrict__ w_ih, const float* __restrict__ w_hh,
    float* __restrict__ wtih, float* __restrict__ wthh) {
  int idx = blockIdx.x * 256 + threadIdx.x;
  if (idx < 192 * 64) {
    wtih[(idx & 63) * 192 + (idx >> 6)] = w_ih[idx];
  } else if (idx < 2 * 192 * 64) {
    int i2 = idx - 192 * 64;
    wthh[(i2 & 63) * 192 + (i2 >> 6)] = w_hh[i2];
  }
}

// ---------------- CSR build ----------------

__global__ __launch_bounds__(256) void count_kernel(
    const int* __restrict__ dst, unsigned* __restrict__ counts, int E) {
  int e = blockIdx.x * 256 + threadIdx.x;
  if (e < E) atomicAdd(&counts[dst[e]], 1u);
}

__global__ __launch_bounds__(1024) void scan_k1(
    const unsigned* __restrict__ counts, unsigned* __restrict__ offs,
    unsigned* __restrict__ bsums, int N) {
  __shared__ unsigned sm[1024];
  int tid = threadIdx.x;
  int i = blockIdx.x * 1024 + tid;
  unsigned v = (i < N) ? counts[i] : 0u;
  sm[tid] = v;
  __syncthreads();
  for (int ofs = 1; ofs < 1024; ofs <<= 1) {
    unsigned add = (tid >= ofs) ? sm[tid - ofs] : 0u;
    __syncthreads();
    sm[tid] += add;
    __syncthreads();
  }
  if (i < N) offs[i] = sm[tid] - v;
  if (tid == 0) bsums[blockIdx.x] = sm[1023];
}

__global__ __launch_bounds__(128) void scan_k2(
    unsigned* __restrict__ bsums, unsigned* __restrict__ offs, int M, int N) {
  __shared__ unsigned sm[128];
  int tid = threadIdx.x;
  unsigned v = (tid < M) ? bsums[tid] : 0u;
  sm[tid] = v;
  __syncthreads();
  for (int ofs = 1; ofs < 128; ofs <<= 1) {
    unsigned add = (tid >= ofs) ? sm[tid - ofs] : 0u;
    __syncthreads();
    sm[tid] += add;
    __syncthreads();
  }
  if (tid < M) bsums[tid] = sm[tid] - v;
  if (tid == 127) offs[N] = sm[127];
}

__global__ __launch_bounds__(256) void scan_k3(
    unsigned* __restrict__ offs, const unsigned* __restrict__ bsums,
    unsigned* __restrict__ cursor, int N) {
  int i = blockIdx.x * 256 + threadIdx.x;
  if (i < N) {
    unsigned o = offs[i] + bsums[i >> 10];
    offs[i] = o;
    cursor[i] = o;
  }
}

__global__ __launch_bounds__(256) void fill_kernel(
    const int* __restrict__ src, const int* __restrict__ dst,
    const int* __restrict__ rel, const float* __restrict__ norm,
    unsigned* __restrict__ cursor, unsigned* __restrict__ packed,
    float* __restrict__ norms, int E) {
  int e = blockIdx.x * 256 + threadIdx.x;
  if (e < E) {
    int d = dst[e];
    unsigned p = atomicAdd(&cursor[d], 1u);
    packed[p] = (unsigned)src[e] | ((unsigned)rel[e] << 20);
    norms[p] = norm[e];
  }
}

// ---------------- transform: t[r][n][e] = sum_d x[n][d] * W[r][d][e] ----------------
// column-per-lane (lane=e), W staged in LDS, 8 nodes/wave; x via wave-uniform s_load.

__global__ __launch_bounds__(256) void transform_kernel(
    const float* __restrict__ x, const float* __restrict__ W,
    float* __restrict__ t, int N) {
  __shared__ float wl[3 * 64 * 64];  // 48KB
  for (int i = threadIdx.x; i < 3 * 64 * 64; i += 256) wl[i] = W[i];
  __syncthreads();
  int lane = threadIdx.x & 63;
  int wid = __builtin_amdgcn_readfirstlane(threadIdx.x >> 6);
  int n0 = blockIdx.x * 32 + wid * 8;
  if (n0 >= N) return;  // N divisible by 32 for this problem
  const float* xr = x + (size_t)n0 * 64;
  float acc[3][8] = {};
#pragma unroll 2
  for (int d = 0; d < 64; ++d) {
    float w0 = wl[d * 64 + lane];
    float w1 = wl[4096 + d * 64 + lane];
    float w2 = wl[8192 + d * 64 + lane];
#pragma unroll
    for (int j = 0; j < 8; ++j) {
      float xv = xr[j * 64 + d];  // wave-uniform -> s_load
      acc[0][j] = fmaf(xv, w0, acc[0][j]);
      acc[1][j] = fmaf(xv, w1, acc[1][j]);
      acc[2][j] = fmaf(xv, w2, acc[2][j]);
    }
  }
#pragma unroll
  for (int r = 0; r < 3; ++r)
#pragma unroll
    for (int j = 0; j < 8; ++j)
      t[((size_t)r * N + n0 + j) * 64 + lane] = acc[r][j];
}

// ---------------- gather: swh[n][c] = sum_{e: dst=n} t[rel][src][c]*norm ----------------

__global__ __launch_bounds__(256) void gather_kernel(
    const float* __restrict__ t, const unsigned* __restrict__ offs,
    const unsigned* __restrict__ packed, const float* __restrict__ norms,
    float* __restrict__ swh, int N) {
  int lane = threadIdx.x & 63;
  int n = __builtin_amdgcn_readfirstlane(blockIdx.x * 4 + (threadIdx.x >> 6));
  if (n >= N) return;
  unsigned a = offs[n], b = offs[n + 1];
  float acc0 = 0.f, acc1 = 0.f;
  unsigned j = a;
  for (; j + 2 <= b; j += 2) {
    unsigned p0 = packed[j];      // uniform -> s_load
    unsigned p1 = packed[j + 1];
    float nv0 = norms[j];
    float nv1 = norms[j + 1];
    const float* r0 = t + ((size_t)(p0 >> 20) * N + (p0 & 0xFFFFFu)) * 64;
    const float* r1 = t + ((size_t)(p1 >> 20) * N + (p1 & 0xFFFFFu)) * 64;
    float v0 = r0[lane];
    float v1 = r1[lane];
    acc0 = fmaf(v0, nv0, acc0);
    acc1 = fmaf(v1, nv1, acc1);
  }
  if (j < b) {
    unsigned p0 = packed[j];
    float nv0 = norms[j];
    acc0 = fmaf(t[((size_t)(p0 >> 20) * N + (p0 & 0xFFFFFu)) * 64 + lane], nv0, acc0);
  }
  swh[(size_t)n * 64 + lane] = acc0 + acc1;
}

// ---------------- fused GRU cell (column-per-lane, 8 nodes/wave) ----------------
// In-place safe: each wave owns rows n0..n0+7 exclusively; all h reads precede stores.

template <int USE_H>
__global__ __launch_bounds__(256) void gru_kernel(
    const float* __restrict__ xin, const float* hin,
    const float* __restrict__ wtih_g, const float* __restrict__ wthh_g,
    const float* __restrict__ b_ih, const float* __restrict__ b_hh,
    float* hout, int N) {
  __shared__ float wl[64 * 192];  // wt_ih staged, 48KB
  for (int i = threadIdx.x; i < 64 * 192; i += 256) wl[i] = wtih_g[i];
  __syncthreads();
  int lane = threadIdx.x & 63;
  int wid = __builtin_amdgcn_readfirstlane(threadIdx.x >> 6);
  int n0 = blockIdx.x * 32 + wid * 8;
  if (n0 >= N) return;
  const float* xr = xin + (size_t)n0 * 64;
  const float* hr = hin + (size_t)n0 * 64;
  float ai[3][8] = {}, ah[3][8] = {};
#pragma unroll 2
  for (int d = 0; d < 64; ++d) {
    float wi0 = wl[d * 192 + lane];
    float wi1 = wl[d * 192 + 64 + lane];
    float wi2 = wl[d * 192 + 128 + lane];
    float wh0 = wthh_g[d * 192 + lane];        // coalesced, L1/L2-resident
    float wh1 = wthh_g[d * 192 + 64 + lane];
    float wh2 = wthh_g[d * 192 + 128 + lane];
#pragma unroll
    for (int j = 0; j < 8; ++j) {
      float xv = xr[j * 64 + d];  // s_load
      ai[0][j] = fmaf(xv, wi0, ai[0][j]);
      ai[1][j] = fmaf(xv, wi1, ai[1][j]);
      ai[2][j] = fmaf(xv, wi2, ai[2][j]);
      if (USE_H) {
        float hv = hr[j * 64 + d];  // s_load
        ah[0][j] = fmaf(hv, wh0, ah[0][j]);
        ah[1][j] = fmaf(hv, wh1, ah[1][j]);
        ah[2][j] = fmaf(hv, wh2, ah[2][j]);
      }
    }
  }
  float bi0 = b_ih[lane], bi1 = b_ih[64 + lane], bi2 = b_ih[128 + lane];
  float bh0 = b_hh[lane], bh1 = b_hh[64 + lane], bh2 = b_hh[128 + lane];
#pragma unroll
  for (int j = 0; j < 8; ++j) {
    float hprev = USE_H ? hr[(size_t)j * 64 + lane] : 0.f;
    float r = 1.f / (1.f + __expf(-(ai[0][j] + bi0 + ah[0][j] + bh0)));
    float z = 1.f / (1.f + __expf(-(ai[1][j] + bi1 + ah[1][j] + bh1)));
    float nn = tanhf(ai[2][j] + bi2 + r * (ah[2][j] + bh2));
    hout[((size_t)n0 + j) * 64 + lane] = (1.f - z) * nn + z * hprev;
  }
}

// ---------------- batchnorm ----------------

__global__ __launch_bounds__(256) void bn_stats_kernel(
    const float* __restrict__ h, float* __restrict__ stats, int N) {
  int tid = threadIdx.x;
  int c = tid & 63;
  float s = 0.f, ss = 0.f;
  for (int n = blockIdx.x * 4 + (tid >> 6); n < N; n += gridDim.x * 4) {
    float v = h[(size_t)n * 64 + c];
    s += v;
    ss += v * v;
  }
  __shared__ float sm[2][256];
  sm[0][tid] = s;
  sm[1][tid] = ss;
  __syncthreads();
  if (tid < 64) {
    s = sm[0][tid] + sm[0][tid + 64] + sm[0][tid + 128] + sm[0][tid + 192];
    ss = sm[1][tid] + sm[1][tid + 64] + sm[1][tid + 128] + sm[1][tid + 192];
    atomicAdd(&stats[tid], s);
    atomicAdd(&stats[64 + tid], ss);
  }
}

__global__ __launch_bounds__(256) void bn_apply_kernel(
    float* out, const float* __restrict__ stats,
    const float* __restrict__ gamma, const float* __restrict__ beta,
    int N, int total) {
  int idx = blockIdx.x * 256 + threadIdx.x;
  if (idx >= total) return;
  int c = idx & 63;
  float invN = 1.f / (float)N;
  float mean = stats[c] * invN;
  float var = stats[64 + c] * invN - mean * mean;
  float sc = rsqrtf(var + 1e-5f) * gamma[c];
  float sh = beta[c] - mean * sc;
  out[idx] = out[idx] * sc + sh;
}

// ---------------- launch ----------------

extern "C" void kernel_launch(void* const* d_in, const int* in_sizes, int n_in,
                              void* d_out, int out_size, void* d_ws, size_t ws_size,
                              hipStream_t stream) {
  const float* h     = (const float*)d_in[0];
  const float* norm  = (const float*)d_in[1];
  const float* W     = (const float*)d_in[2];
  const float* w_ih  = (const float*)d_in[3];
  const float* w_hh  = (const float*)d_in[4];
  const float* b_ih  = (const float*)d_in[5];
  const float* b_hh  = (const float*)d_in[6];
  const float* gamma = (const float*)d_in[7];
  const float* beta  = (const float*)d_in[8];
  const int* src     = (const int*)d_in[9];
  const int* dst     = (const int*)d_in[10];
  const int* rel     = (const int*)d_in[11];
  float* out = (float*)d_out;

  const int N = in_sizes[0] / 64;
  const int E = in_sizes[1];

  char* w = (char*)d_ws;
  float* t = (float*)w;            w += (size_t)3 * N * 64 * 4;
  float* swh = (float*)w;          w += (size_t)N * 64 * 4;
  float* wtih = (float*)w;         w += 192 * 64 * 4;
  float* wthh = (float*)w;         w += 192 * 64 * 4;
  unsigned* offs = (unsigned*)w;   w += ((size_t)N + 4) * 4;
  unsigned* cursor = (unsigned*)w; w += (size_t)N * 4;
  unsigned* packed = (unsigned*)w; w += (size_t)E * 4;
  float* norms = (float*)w;        w += (size_t)E * 4;
  unsigned* bsums = (unsigned*)w;  w += 128 * 4;
  float* stats = (float*)w;        w += 128 * 4;

  const int M = (N + 1023) / 1024;
  const int NB = (N + 31) / 32;

  hipMemsetAsync(cursor, 0, (size_t)N * 4, stream);
  hipMemsetAsync(stats, 0, 128 * 4, stream);

  transpose_w_kernel<<<96, 256, 0, stream>>>(w_ih, w_hh, wtih, wthh);

  // CSR over dst (graph is layer-invariant)
  count_kernel<<<(E + 255) / 256, 256, 0, stream>>>(dst, cursor, E);
  scan_k1<<<M, 1024, 0, stream>>>(cursor, offs, bsums, N);
  scan_k2<<<1, 128, 0, stream>>>(bsums, offs, M, N);
  scan_k3<<<(N + 255) / 256, 256, 0, stream>>>(offs, bsums, cursor, N);
  fill_kernel<<<(E + 255) / 256, 256, 0, stream>>>(src, dst, rel, norm, cursor,
                                                   packed, norms, E);

  // layer 0: hstate = 0
  transform_kernel<<<NB, 256, 0, stream>>>(h, W, t, N);
  gather_kernel<<<(N + 3) / 4, 256, 0, stream>>>(t, offs, packed, norms, swh, N);
  gru_kernel<0><<<NB, 256, 0, stream>>>(swh, out, wtih, wthh, b_ih, b_hh, out, N);

  // layer 1: hstate = out (in-place safe)
  transform_kernel<<<NB, 256, 0, stream>>>(out, W, t, N);
  gather_kernel<<<(N + 3) / 4, 256, 0, stream>>>(t, offs, packed, norms, swh, N);
  gru_kernel<1><<<NB, 256, 0, stream>>>(swh, out, wtih, wthh, b_ih, b_hh, out, N);

  bn_stats_kernel<<<256, 256, 0, stream>>>(out, stats, N);
  int total = N * 64;
  bn_apply_kernel<<<(total + 255) / 256, 256, 0, stream>>>(out, stats, gamma,
                                                           beta, N, total);
}

// Round 4
// 405.328 us; speedup vs baseline: 2.3825x; 1.3427x over previous
//
#include <hip/hip_runtime.h>

typedef __bf16 bf16x8 __attribute__((ext_vector_type(8)));
typedef float f32x4 __attribute__((ext_vector_type(4)));
typedef short short8 __attribute__((ext_vector_type(8)));

#define MFMA16(a, b, c) __builtin_amdgcn_mfma_f32_16x16x32_bf16(a, b, c, 0, 0, 0)

__device__ inline unsigned short bf16_rne(float x) {
  unsigned u = __builtin_bit_cast(unsigned, x);
  return (unsigned short)((u + 0x7FFFu + ((u >> 16) & 1u)) >> 16);
}
__device__ inline float bf16_tof(unsigned short s) {
  unsigned u = ((unsigned)s) << 16;
  return __builtin_bit_cast(float, u);
}
__device__ inline void split2(float x, unsigned short* hi, unsigned short* lo) {
  unsigned short h = bf16_rne(x);
  *hi = h;
  *lo = bf16_rne(x - bf16_tof(h));
}

// ---------------- fp32 -> (hi, lo) bf16 split ----------------

__global__ __launch_bounds__(256) void conv_split_kernel(
    const float* __restrict__ x, unsigned short* __restrict__ xhi,
    unsigned short* __restrict__ xlo, int total4) {
  int i = blockIdx.x * 256 + threadIdx.x;
  if (i < total4) {
    float4 v = ((const float4*)x)[i];
    ushort4 h, l;
    split2(v.x, &h.x, &l.x);
    split2(v.y, &h.y, &l.y);
    split2(v.z, &h.z, &l.z);
    split2(v.w, &h.w, &l.w);
    ((ushort4*)xhi)[i] = h;
    ((ushort4*)xlo)[i] = l;
  }
}

// ---------------- weight frag prep ----------------
// frag layout per set: hi[12288] then lo[12288]; index ((tci*2+ks)*64+lane)*8+j
// B[k][c]: set0 (transform): W[c>>6][k][c&63]; set1: w_ih[c][k]; set2: w_hh[c][k]

__global__ __launch_bounds__(256) void wprep_kernel(
    const float* __restrict__ W, const float* __restrict__ w_ih,
    const float* __restrict__ w_hh, unsigned short* __restrict__ frags) {
  int idx = blockIdx.x * 256 + threadIdx.x;
  if (idx >= 3 * 12 * 2 * 64) return;
  int lane = idx & 63;
  int ks = (idx >> 6) & 1;
  int tci = (idx >> 7) % 12;
  int set = idx / (12 * 2 * 64);
  int c = tci * 16 + (lane & 15);
  unsigned short* hi = frags + (size_t)set * 2 * 12288;
  unsigned short* lo = hi + 12288;
  size_t dbase = ((size_t)(tci * 2 + ks) * 64 + lane) * 8;
#pragma unroll
  for (int j = 0; j < 8; ++j) {
    int k = ks * 32 + ((lane >> 4) << 3) + j;
    float v;
    if (set == 0) v = W[((c >> 6) << 12) + (k << 6) + (c & 63)];
    else if (set == 1) v = w_ih[(c << 6) + k];
    else v = w_hh[(c << 6) + k];
    unsigned short h, l;
    split2(v, &h, &l);
    hi[dbase + j] = h;
    lo[dbase + j] = l;
  }
}

// ---------------- CSR build ----------------

__global__ __launch_bounds__(256) void count_kernel(
    const int* __restrict__ dst, unsigned* __restrict__ counts, int E) {
  int e = blockIdx.x * 256 + threadIdx.x;
  if (e < E) atomicAdd(&counts[dst[e]], 1u);
}

__global__ __launch_bounds__(1024) void scan_k1(
    const unsigned* __restrict__ counts, unsigned* __restrict__ offs,
    unsigned* __restrict__ bsums, int N) {
  __shared__ unsigned sm[1024];
  int tid = threadIdx.x;
  int i = blockIdx.x * 1024 + tid;
  unsigned v = (i < N) ? counts[i] : 0u;
  sm[tid] = v;
  __syncthreads();
  for (int ofs = 1; ofs < 1024; ofs <<= 1) {
    unsigned add = (tid >= ofs) ? sm[tid - ofs] : 0u;
    __syncthreads();
    sm[tid] += add;
    __syncthreads();
  }
  if (i < N) offs[i] = sm[tid] - v;
  if (tid == 0) bsums[blockIdx.x] = sm[1023];
}

__global__ __launch_bounds__(128) void scan_k2(
    unsigned* __restrict__ bsums, unsigned* __restrict__ offs, int M, int N) {
  __shared__ unsigned sm[128];
  int tid = threadIdx.x;
  unsigned v = (tid < M) ? bsums[tid] : 0u;
  sm[tid] = v;
  __syncthreads();
  for (int ofs = 1; ofs < 128; ofs <<= 1) {
    unsigned add = (tid >= ofs) ? sm[tid - ofs] : 0u;
    __syncthreads();
    sm[tid] += add;
    __syncthreads();
  }
  if (tid < M) bsums[tid] = sm[tid] - v;
  if (tid == 127) offs[N] = sm[127];
}

__global__ __launch_bounds__(256) void scan_k3(
    unsigned* __restrict__ offs, const unsigned* __restrict__ bsums,
    unsigned* __restrict__ cursor, int N) {
  int i = blockIdx.x * 256 + threadIdx.x;
  if (i < N) {
    unsigned o = offs[i] + bsums[i >> 10];
    offs[i] = o;
    cursor[i] = o;
  }
}

__global__ __launch_bounds__(256) void fill_kernel(
    const int* __restrict__ src, const int* __restrict__ dst,
    const int* __restrict__ rel, const float* __restrict__ norm,
    unsigned* __restrict__ cursor, unsigned* __restrict__ packed,
    float* __restrict__ norms, int E) {
  int e = blockIdx.x * 256 + threadIdx.x;
  if (e < E) {
    int d = dst[e];
    unsigned p = atomicAdd(&cursor[d], 1u);
    packed[p] = (unsigned)src[e] | ((unsigned)rel[e] << 20);
    norms[p] = norm[e];
  }
}

// ---------------- transform (MFMA): t[r][n][e] = sum_d x[n][d] W[r][d][e] ----------------

__global__ __launch_bounds__(256) void transform_kernel(
    const unsigned short* __restrict__ xhi, const unsigned short* __restrict__ xlo,
    const unsigned short* __restrict__ wfrag, float* __restrict__ t, int N, int NT) {
  int lane = threadIdx.x & 63;
  int w = threadIdx.x >> 6;
  bf16x8 bh[3][2], bl[3][2];
  const short8* fh = (const short8*)wfrag;
  const short8* fl = (const short8*)(wfrag + 12288);
#pragma unroll
  for (int ct = 0; ct < 3; ++ct)
#pragma unroll
    for (int ks = 0; ks < 2; ++ks) {
      int tci = w * 3 + ct;
      bh[ct][ks] = __builtin_bit_cast(bf16x8, fh[(tci * 2 + ks) * 64 + lane]);
      bl[ct][ks] = __builtin_bit_cast(bf16x8, fl[(tci * 2 + ks) * 64 + lane]);
    }
  int r15 = lane & 15, kq = lane >> 4;
  for (int nt = blockIdx.x; nt < NT; nt += gridDim.x) {
    int n0 = nt * 16;
    int row = n0 + r15;
    if (row >= N) row = N - 1;
    const short8* ah = (const short8*)(xhi + (((size_t)row) << 6) + (kq << 3));
    const short8* al = (const short8*)(xlo + (((size_t)row) << 6) + (kq << 3));
    bf16x8 axh[2], axl[2];
    axh[0] = __builtin_bit_cast(bf16x8, ah[0]);
    axh[1] = __builtin_bit_cast(bf16x8, ah[4]);
    axl[0] = __builtin_bit_cast(bf16x8, al[0]);
    axl[1] = __builtin_bit_cast(bf16x8, al[4]);
#pragma unroll
    for (int ct = 0; ct < 3; ++ct) {
      f32x4 acc = {0.f, 0.f, 0.f, 0.f};
#pragma unroll
      for (int ks = 0; ks < 2; ++ks) {
        acc = MFMA16(axh[ks], bh[ct][ks], acc);
        acc = MFMA16(axh[ks], bl[ct][ks], acc);
        acc = MFMA16(axl[ks], bh[ct][ks], acc);
      }
      int c = (w * 3 + ct) * 16 + r15;
      int rrel = c >> 6, e = c & 63;
      float* tb = t + (((size_t)rrel * N) << 6) + e;
#pragma unroll
      for (int reg = 0; reg < 4; ++reg) {
        int n = n0 + (kq << 2) + reg;
        if (n < N) tb[((size_t)n) << 6] = acc[reg];
      }
    }
  }
}

// ---------------- gather: swh (bf16 split) ----------------

__global__ __launch_bounds__(256) void gather_kernel(
    const float* __restrict__ t, const unsigned* __restrict__ offs,
    const unsigned* __restrict__ packed, const float* __restrict__ norms,
    unsigned short* __restrict__ swhhi, unsigned short* __restrict__ swhlo, int N) {
  int lane = threadIdx.x & 63;
  int n = __builtin_amdgcn_readfirstlane(blockIdx.x * 4 + (threadIdx.x >> 6));
  if (n >= N) return;
  unsigned a = offs[n], b = offs[n + 1];
  float acc0 = 0.f, acc1 = 0.f;
  unsigned j = a;
  for (; j + 2 <= b; j += 2) {
    unsigned p0 = packed[j];
    unsigned p1 = packed[j + 1];
    float nv0 = norms[j];
    float nv1 = norms[j + 1];
    const float* r0 = t + ((size_t)(p0 >> 20) * N + (p0 & 0xFFFFFu)) * 64;
    const float* r1 = t + ((size_t)(p1 >> 20) * N + (p1 & 0xFFFFFu)) * 64;
    float v0 = r0[lane];
    float v1 = r1[lane];
    acc0 = fmaf(v0, nv0, acc0);
    acc1 = fmaf(v1, nv1, acc1);
  }
  if (j < b) {
    unsigned p0 = packed[j];
    float nv0 = norms[j];
    acc0 = fmaf(t[((size_t)(p0 >> 20) * N + (p0 & 0xFFFFFu)) * 64 + lane], nv0, acc0);
  }
  float acc = acc0 + acc1;
  unsigned short h, l;
  split2(acc, &h, &l);
  swhhi[(size_t)n * 64 + lane] = h;
  swhlo[(size_t)n * 64 + lane] = l;
}

// ---------------- fused GRU (MFMA + LDS gate exchange) ----------------

template <int USE_H, int WRITE_SPLIT>
__global__ __launch_bounds__(256) void gru_kernel(
    const unsigned short* __restrict__ xhi, const unsigned short* __restrict__ xlo,
    const unsigned short* __restrict__ hhi, const unsigned short* __restrict__ hlo,
    const float* __restrict__ hprev,
    const unsigned short* __restrict__ wfi, const unsigned short* __restrict__ wfh,
    const float* __restrict__ b_ih, const float* __restrict__ b_hh,
    float* __restrict__ hout, unsigned short* __restrict__ houthi,
    unsigned short* __restrict__ houtlo, int N, int NT) {
  __shared__ float gi[16][204];
  __shared__ float gh[16][204];
  __shared__ float bias[2][192];
  for (int i = threadIdx.x; i < 192; i += 256) {
    bias[0][i] = b_ih[i];
    bias[1][i] = b_hh[i];
  }
  int lane = threadIdx.x & 63;
  int w = threadIdx.x >> 6;
  bf16x8 bih[3][2], bil[3][2], bhh[3][2], bhl[3][2];
  {
    const short8* fih = (const short8*)wfi;
    const short8* fil = (const short8*)(wfi + 12288);
    const short8* fhh = (const short8*)wfh;
    const short8* fhl = (const short8*)(wfh + 12288);
#pragma unroll
    for (int ct = 0; ct < 3; ++ct)
#pragma unroll
      for (int ks = 0; ks < 2; ++ks) {
        int tci = w * 3 + ct;
        bih[ct][ks] = __builtin_bit_cast(bf16x8, fih[(tci * 2 + ks) * 64 + lane]);
        bil[ct][ks] = __builtin_bit_cast(bf16x8, fil[(tci * 2 + ks) * 64 + lane]);
        if (USE_H) {
          bhh[ct][ks] = __builtin_bit_cast(bf16x8, fhh[(tci * 2 + ks) * 64 + lane]);
          bhl[ct][ks] = __builtin_bit_cast(bf16x8, fhl[(tci * 2 + ks) * 64 + lane]);
        }
      }
  }
  __syncthreads();
  int r15 = lane & 15, kq = lane >> 4;
  int tnode = threadIdx.x >> 4;
  int c4 = (threadIdx.x & 15) * 4;

  for (int nt = blockIdx.x; nt < NT; nt += gridDim.x) {
    int n0 = nt * 16;
    int row = n0 + r15;
    if (row >= N) row = N - 1;
    bf16x8 axh[2], axl[2], ahh2[2], ahl2[2];
    {
      const short8* ax0 = (const short8*)(xhi + (((size_t)row) << 6) + (kq << 3));
      const short8* ax1 = (const short8*)(xlo + (((size_t)row) << 6) + (kq << 3));
      axh[0] = __builtin_bit_cast(bf16x8, ax0[0]);
      axh[1] = __builtin_bit_cast(bf16x8, ax0[4]);
      axl[0] = __builtin_bit_cast(bf16x8, ax1[0]);
      axl[1] = __builtin_bit_cast(bf16x8, ax1[4]);
      if (USE_H) {
        const short8* ah0 = (const short8*)(hhi + (((size_t)row) << 6) + (kq << 3));
        const short8* ah1 = (const short8*)(hlo + (((size_t)row) << 6) + (kq << 3));
        ahh2[0] = __builtin_bit_cast(bf16x8, ah0[0]);
        ahh2[1] = __builtin_bit_cast(bf16x8, ah0[4]);
        ahl2[0] = __builtin_bit_cast(bf16x8, ah1[0]);
        ahl2[1] = __builtin_bit_cast(bf16x8, ah1[4]);
      }
    }
#pragma unroll
    for (int ct = 0; ct < 3; ++ct) {
      f32x4 ax = {0.f, 0.f, 0.f, 0.f};
      f32x4 ah = {0.f, 0.f, 0.f, 0.f};
#pragma unroll
      for (int ks = 0; ks < 2; ++ks) {
        ax = MFMA16(axh[ks], bih[ct][ks], ax);
        ax = MFMA16(axh[ks], bil[ct][ks], ax);
        ax = MFMA16(axl[ks], bih[ct][ks], ax);
        if (USE_H) {
          ah = MFMA16(ahh2[ks], bhh[ct][ks], ah);
          ah = MFMA16(ahh2[ks], bhl[ct][ks], ah);
          ah = MFMA16(ahl2[ks], bhh[ct][ks], ah);
        }
      }
      int c = (w * 3 + ct) * 16 + r15;
#pragma unroll
      for (int reg = 0; reg < 4; ++reg) {
        gi[(kq << 2) + reg][c] = ax[reg];
        if (USE_H) gh[(kq << 2) + reg][c] = ah[reg];
      }
    }
    __syncthreads();
    // elementwise gates: thread -> (node tnode, cols c4..c4+3)
    int n = n0 + tnode;
    if (n < N) {
      float4 hp;
      if (USE_H) hp = *(const float4*)(hprev + (((size_t)n) << 6) + c4);
      else hp = make_float4(0.f, 0.f, 0.f, 0.f);
      float hpv[4] = {hp.x, hp.y, hp.z, hp.w};
      float ov[4];
      ushort4 oh, ol;
      unsigned short* ohp = &oh.x;
      unsigned short* olp = &ol.x;
#pragma unroll
      for (int i = 0; i < 4; ++i) {
        int c = c4 + i;
        float gir = gi[tnode][c] + bias[0][c];
        float giz = gi[tnode][c + 64] + bias[0][c + 64];
        float gin = gi[tnode][c + 128] + bias[0][c + 128];
        float ghr = (USE_H ? gh[tnode][c] : 0.f) + bias[1][c];
        float ghz = (USE_H ? gh[tnode][c + 64] : 0.f) + bias[1][c + 64];
        float ghn = (USE_H ? gh[tnode][c + 128] : 0.f) + bias[1][c + 128];
        float r = 1.f / (1.f + __expf(-(gir + ghr)));
        float z = 1.f / (1.f + __expf(-(giz + ghz)));
        float nn = tanhf(gin + r * ghn);
        float o = (1.f - z) * nn + z * hpv[i];
        ov[i] = o;
        if (WRITE_SPLIT) split2(o, &ohp[i], &olp[i]);
      }
      *(float4*)(hout + (((size_t)n) << 6) + c4) = make_float4(ov[0], ov[1], ov[2], ov[3]);
      if (WRITE_SPLIT) {
        *(ushort4*)(houthi + (((size_t)n) << 6) + c4) = oh;
        *(ushort4*)(houtlo + (((size_t)n) << 6) + c4) = ol;
      }
    }
    __syncthreads();
  }
}

// ---------------- batchnorm ----------------

__global__ __launch_bounds__(256) void bn_stats_kernel(
    const float* __restrict__ h, float* __restrict__ stats, int N) {
  int tid = threadIdx.x;
  int c = tid & 63;
  float s = 0.f, ss = 0.f;
  for (int n = blockIdx.x * 4 + (tid >> 6); n < N; n += gridDim.x * 4) {
    float v = h[(size_t)n * 64 + c];
    s += v;
    ss += v * v;
  }
  __shared__ float sm[2][256];
  sm[0][tid] = s;
  sm[1][tid] = ss;
  __syncthreads();
  if (tid < 64) {
    s = sm[0][tid] + sm[0][tid + 64] + sm[0][tid + 128] + sm[0][tid + 192];
    ss = sm[1][tid] + sm[1][tid + 64] + sm[1][tid + 128] + sm[1][tid + 192];
    atomicAdd(&stats[tid], s);
    atomicAdd(&stats[64 + tid], ss);
  }
}

__global__ __launch_bounds__(256) void bn_apply_kernel(
    float* out, const float* __restrict__ stats,
    const float* __restrict__ gamma, const float* __restrict__ beta,
    int N, int total) {
  int idx = blockIdx.x * 256 + threadIdx.x;
  if (idx >= total) return;
  int c = idx & 63;
  float invN = 1.f / (float)N;
  float mean = stats[c] * invN;
  float var = stats[64 + c] * invN - mean * mean;
  float sc = rsqrtf(var + 1e-5f) * gamma[c];
  float sh = beta[c] - mean * sc;
  out[idx] = out[idx] * sc + sh;
}

// ---------------- launch ----------------

extern "C" void kernel_launch(void* const* d_in, const int* in_sizes, int n_in,
                              void* d_out, int out_size, void* d_ws, size_t ws_size,
                              hipStream_t stream) {
  const float* h     = (const float*)d_in[0];
  const float* norm  = (const float*)d_in[1];
  const float* W     = (const float*)d_in[2];
  const float* w_ih  = (const float*)d_in[3];
  const float* w_hh  = (const float*)d_in[4];
  const float* b_ih  = (const float*)d_in[5];
  const float* b_hh  = (const float*)d_in[6];
  const float* gamma = (const float*)d_in[7];
  const float* beta  = (const float*)d_in[8];
  const int* src     = (const int*)d_in[9];
  const int* dst     = (const int*)d_in[10];
  const int* rel     = (const int*)d_in[11];
  float* out = (float*)d_out;

  const int N = in_sizes[0] / 64;
  const int E = in_sizes[1];
  const int NT = (N + 15) / 16;

  char* wsp = (char*)d_ws;
  float* t = (float*)wsp;              wsp += (size_t)3 * N * 64 * 4;
  unsigned short* xhi = (unsigned short*)wsp; wsp += (size_t)N * 64 * 2;
  unsigned short* xlo = (unsigned short*)wsp; wsp += (size_t)N * 64 * 2;
  unsigned short* swhhi = (unsigned short*)wsp; wsp += (size_t)N * 64 * 2;
  unsigned short* swhlo = (unsigned short*)wsp; wsp += (size_t)N * 64 * 2;
  unsigned short* frags = (unsigned short*)wsp; wsp += 6 * 12288 * 2;
  unsigned* offs = (unsigned*)wsp;   wsp += ((size_t)N + 4) * 4;
  unsigned* cursor = (unsigned*)wsp; wsp += (size_t)N * 4;
  unsigned* packed = (unsigned*)wsp; wsp += (size_t)E * 4;
  float* norms = (float*)wsp;        wsp += (size_t)E * 4;
  unsigned* bsums = (unsigned*)wsp;  wsp += 128 * 4;
  float* stats = (float*)wsp;        wsp += 128 * 4;

  const unsigned short* frag_t = frags;
  const unsigned short* frag_i = frags + 2 * 12288;
  const unsigned short* frag_h = frags + 4 * 12288;

  const int M = (N + 1023) / 1024;

  hipMemsetAsync(cursor, 0, (size_t)N * 4, stream);
  hipMemsetAsync(stats, 0, 128 * 4, stream);

  wprep_kernel<<<18, 256, 0, stream>>>(W, w_ih, w_hh, frags);
  conv_split_kernel<<<(N * 16 + 255) / 256, 256, 0, stream>>>(h, xhi, xlo, N * 16);

  // CSR over dst (graph is layer-invariant)
  count_kernel<<<(E + 255) / 256, 256, 0, stream>>>(dst, cursor, E);
  scan_k1<<<M, 1024, 0, stream>>>(cursor, offs, bsums, N);
  scan_k2<<<1, 128, 0, stream>>>(bsums, offs, M, N);
  scan_k3<<<(N + 255) / 256, 256, 0, stream>>>(offs, bsums, cursor, N);
  fill_kernel<<<(E + 255) / 256, 256, 0, stream>>>(src, dst, rel, norm, cursor,
                                                   packed, norms, E);

  // layer 0 (hstate = 0): gru writes h1 fp32 -> out, h1 split -> xhi/xlo
  transform_kernel<<<1024, 256, 0, stream>>>(xhi, xlo, frag_t, t, N, NT);
  gather_kernel<<<(N + 3) / 4, 256, 0, stream>>>(t, offs, packed, norms, swhhi, swhlo, N);
  gru_kernel<0, 1><<<1024, 256, 0, stream>>>(swhhi, swhlo, nullptr, nullptr, nullptr,
                                             frag_i, frag_h, b_ih, b_hh,
                                             out, xhi, xlo, N, NT);

  // layer 1: transform reads h1 split; gru h-path reads h1 split, hprev = out
  transform_kernel<<<1024, 256, 0, stream>>>(xhi, xlo, frag_t, t, N, NT);
  gather_kernel<<<(N + 3) / 4, 256, 0, stream>>>(t, offs, packed, norms, swhhi, swhlo, N);
  gru_kernel<1, 0><<<1024, 256, 0, stream>>>(swhhi, swhlo, xhi, xlo, out,
                                             frag_i, frag_h, b_ih, b_hh,
                                             out, nullptr, nullptr, N, NT);

  bn_stats_kernel<<<256, 256, 0, stream>>>(out, stats, N);
  int total = N * 64;
  bn_apply_kernel<<<(total + 255) / 256, 256, 0, stream>>>(out, stats, gamma,
                                                           beta, N, total);
}

// Round 5
// 391.527 us; speedup vs baseline: 2.4665x; 1.0352x over previous
//
#include <hip/hip_runtime.h>

typedef __bf16 bf16x8 __attribute__((ext_vector_type(8)));
typedef float f32x4 __attribute__((ext_vector_type(4)));
typedef short short8 __attribute__((ext_vector_type(8)));

#define MFMA16(a, b, c) __builtin_amdgcn_mfma_f32_16x16x32_bf16(a, b, c, 0, 0, 0)

__device__ inline unsigned short bf16_rne(float x) {
  unsigned u = __builtin_bit_cast(unsigned, x);
  return (unsigned short)((u + 0x7FFFu + ((u >> 16) & 1u)) >> 16);
}
__device__ inline float bf16_tof(unsigned short s) {
  unsigned u = ((unsigned)s) << 16;
  return __builtin_bit_cast(float, u);
}
__device__ inline void split2(float x, unsigned short* hi, unsigned short* lo) {
  unsigned short h = bf16_rne(x);
  *hi = h;
  *lo = bf16_rne(x - bf16_tof(h));
}

// ---------------- fp32 -> (hi, lo) bf16 split ----------------

__global__ __launch_bounds__(256) void conv_split_kernel(
    const float* __restrict__ x, unsigned short* __restrict__ xhi,
    unsigned short* __restrict__ xlo, int total4) {
  int i = blockIdx.x * 256 + threadIdx.x;
  if (i < total4) {
    float4 v = ((const float4*)x)[i];
    ushort4 h, l;
    split2(v.x, &h.x, &l.x);
    split2(v.y, &h.y, &l.y);
    split2(v.z, &h.z, &l.z);
    split2(v.w, &h.w, &l.w);
    ((ushort4*)xhi)[i] = h;
    ((ushort4*)xlo)[i] = l;
  }
}

// ---------------- weight frag prep ----------------

__global__ __launch_bounds__(256) void wprep_kernel(
    const float* __restrict__ W, const float* __restrict__ w_ih,
    const float* __restrict__ w_hh, unsigned short* __restrict__ frags) {
  int idx = blockIdx.x * 256 + threadIdx.x;
  if (idx >= 3 * 12 * 2 * 64) return;
  int lane = idx & 63;
  int ks = (idx >> 6) & 1;
  int tci = (idx >> 7) % 12;
  int set = idx / (12 * 2 * 64);
  int c = tci * 16 + (lane & 15);
  unsigned short* hi = frags + (size_t)set * 2 * 12288;
  unsigned short* lo = hi + 12288;
  size_t dbase = ((size_t)(tci * 2 + ks) * 64 + lane) * 8;
#pragma unroll
  for (int j = 0; j < 8; ++j) {
    int k = ks * 32 + ((lane >> 4) << 3) + j;
    float v;
    if (set == 0) v = W[((c >> 6) << 12) + (k << 6) + (c & 63)];
    else if (set == 1) v = w_ih[(c << 6) + k];
    else v = w_hh[(c << 6) + k];
    unsigned short h, l;
    split2(v, &h, &l);
    hi[dbase + j] = h;
    lo[dbase + j] = l;
  }
}

// ---------------- CSR build ----------------

__global__ __launch_bounds__(256) void count_kernel(
    const int* __restrict__ dst, unsigned* __restrict__ counts, int E) {
  int base = (blockIdx.x * 256 + threadIdx.x) * 4;
  if (base + 4 <= E) {
    int4 d = *(const int4*)(dst + base);
    atomicAdd(&counts[d.x], 1u);
    atomicAdd(&counts[d.y], 1u);
    atomicAdd(&counts[d.z], 1u);
    atomicAdd(&counts[d.w], 1u);
  } else {
    for (int k = base; k < E; ++k) atomicAdd(&counts[dst[k]], 1u);
  }
}

__global__ __launch_bounds__(1024) void scan_k1(
    const unsigned* __restrict__ counts, unsigned* __restrict__ offs,
    unsigned* __restrict__ bsums, int N) {
  __shared__ unsigned sm[1024];
  int tid = threadIdx.x;
  int i = blockIdx.x * 1024 + tid;
  unsigned v = (i < N) ? counts[i] : 0u;
  sm[tid] = v;
  __syncthreads();
  for (int ofs = 1; ofs < 1024; ofs <<= 1) {
    unsigned add = (tid >= ofs) ? sm[tid - ofs] : 0u;
    __syncthreads();
    sm[tid] += add;
    __syncthreads();
  }
  if (i < N) offs[i] = sm[tid] - v;
  if (tid == 0) bsums[blockIdx.x] = sm[1023];
}

__global__ __launch_bounds__(128) void scan_k2(
    unsigned* __restrict__ bsums, unsigned* __restrict__ offs, int M, int N) {
  __shared__ unsigned sm[128];
  int tid = threadIdx.x;
  unsigned v = (tid < M) ? bsums[tid] : 0u;
  sm[tid] = v;
  __syncthreads();
  for (int ofs = 1; ofs < 128; ofs <<= 1) {
    unsigned add = (tid >= ofs) ? sm[tid - ofs] : 0u;
    __syncthreads();
    sm[tid] += add;
    __syncthreads();
  }
  if (tid < M) bsums[tid] = sm[tid] - v;
  if (tid == 127) offs[N] = sm[127];
}

__global__ __launch_bounds__(256) void scan_k3(
    unsigned* __restrict__ offs, const unsigned* __restrict__ bsums,
    unsigned* __restrict__ cursor, int N) {
  int i = blockIdx.x * 256 + threadIdx.x;
  if (i < N) {
    unsigned o = offs[i] + bsums[i >> 10];
    offs[i] = o;
    cursor[i] = o;
  }
}

// single interleaved 8B record per edge: {src|rel<<20, norm bits}
__global__ __launch_bounds__(256) void fill_kernel(
    const int* __restrict__ src, const int* __restrict__ dst,
    const int* __restrict__ rel, const float* __restrict__ norm,
    unsigned* __restrict__ cursor, uint2* __restrict__ epack, int E) {
  int e = blockIdx.x * 256 + threadIdx.x;
  if (e < E) {
    int d = dst[e];
    unsigned p = atomicAdd(&cursor[d], 1u);
    uint2 rec;
    rec.x = (unsigned)src[e] | ((unsigned)rel[e] << 20);
    rec.y = __builtin_bit_cast(unsigned, norm[e]);
    epack[p] = rec;
  }
}

// ---------------- transform (MFMA): t[r][n][e] = sum_d x[n][d] W[r][d][e] ----------------

__global__ __launch_bounds__(256) void transform_kernel(
    const unsigned short* __restrict__ xhi, const unsigned short* __restrict__ xlo,
    const unsigned short* __restrict__ wfrag, float* __restrict__ t, int N, int NT) {
  int lane = threadIdx.x & 63;
  int w = threadIdx.x >> 6;
  bf16x8 bh[3][2], bl[3][2];
  const short8* fh = (const short8*)wfrag;
  const short8* fl = (const short8*)(wfrag + 12288);
#pragma unroll
  for (int ct = 0; ct < 3; ++ct)
#pragma unroll
    for (int ks = 0; ks < 2; ++ks) {
      int tci = w * 3 + ct;
      bh[ct][ks] = __builtin_bit_cast(bf16x8, fh[(tci * 2 + ks) * 64 + lane]);
      bl[ct][ks] = __builtin_bit_cast(bf16x8, fl[(tci * 2 + ks) * 64 + lane]);
    }
  int r15 = lane & 15, kq = lane >> 4;
  for (int nt = blockIdx.x; nt < NT; nt += gridDim.x) {
    int n0 = nt * 16;
    int row = n0 + r15;
    if (row >= N) row = N - 1;
    const short8* ah = (const short8*)(xhi + (((size_t)row) << 6) + (kq << 3));
    const short8* al = (const short8*)(xlo + (((size_t)row) << 6) + (kq << 3));
    bf16x8 axh[2], axl[2];
    axh[0] = __builtin_bit_cast(bf16x8, ah[0]);
    axh[1] = __builtin_bit_cast(bf16x8, ah[4]);
    axl[0] = __builtin_bit_cast(bf16x8, al[0]);
    axl[1] = __builtin_bit_cast(bf16x8, al[4]);
#pragma unroll
    for (int ct = 0; ct < 3; ++ct) {
      f32x4 acc = {0.f, 0.f, 0.f, 0.f};
#pragma unroll
      for (int ks = 0; ks < 2; ++ks) {
        acc = MFMA16(axh[ks], bh[ct][ks], acc);
        acc = MFMA16(axh[ks], bl[ct][ks], acc);
        acc = MFMA16(axl[ks], bh[ct][ks], acc);
      }
      int c = (w * 3 + ct) * 16 + r15;
      int rrel = c >> 6, e = c & 63;
      float* tb = t + (((size_t)rrel * N) << 6) + e;
#pragma unroll
      for (int reg = 0; reg < 4; ++reg) {
        int n = n0 + (kq << 2) + reg;
        if (n < N) tb[((size_t)n) << 6] = acc[reg];
      }
    }
  }
}

// ---------------- gather: swh (bf16 split) ----------------

__global__ __launch_bounds__(256) void gather_kernel(
    const float* __restrict__ t, const unsigned* __restrict__ offs,
    const uint2* __restrict__ epack,
    unsigned short* __restrict__ swhhi, unsigned short* __restrict__ swhlo, int N) {
  int lane = threadIdx.x & 63;
  int n = __builtin_amdgcn_readfirstlane(blockIdx.x * 4 + (threadIdx.x >> 6));
  if (n >= N) return;
  unsigned a = offs[n], b = offs[n + 1];
  float acc0 = 0.f, acc1 = 0.f, acc2 = 0.f, acc3 = 0.f;
  unsigned j = a;
  for (; j + 4 <= b; j += 4) {
    uint2 e0 = epack[j];      // uniform -> s_load
    uint2 e1 = epack[j + 1];
    uint2 e2 = epack[j + 2];
    uint2 e3 = epack[j + 3];
    const float* r0 = t + ((size_t)(e0.x >> 20) * N + (e0.x & 0xFFFFFu)) * 64;
    const float* r1 = t + ((size_t)(e1.x >> 20) * N + (e1.x & 0xFFFFFu)) * 64;
    const float* r2 = t + ((size_t)(e2.x >> 20) * N + (e2.x & 0xFFFFFu)) * 64;
    const float* r3 = t + ((size_t)(e3.x >> 20) * N + (e3.x & 0xFFFFFu)) * 64;
    float v0 = r0[lane];
    float v1 = r1[lane];
    float v2 = r2[lane];
    float v3 = r3[lane];
    acc0 = fmaf(v0, __builtin_bit_cast(float, e0.y), acc0);
    acc1 = fmaf(v1, __builtin_bit_cast(float, e1.y), acc1);
    acc2 = fmaf(v2, __builtin_bit_cast(float, e2.y), acc2);
    acc3 = fmaf(v3, __builtin_bit_cast(float, e3.y), acc3);
  }
  for (; j < b; ++j) {
    uint2 e0 = epack[j];
    acc0 = fmaf(t[((size_t)(e0.x >> 20) * N + (e0.x & 0xFFFFFu)) * 64 + lane],
                __builtin_bit_cast(float, e0.y), acc0);
  }
  float acc = (acc0 + acc1) + (acc2 + acc3);
  unsigned short h, l;
  split2(acc, &h, &l);
  swhhi[(size_t)n * 64 + lane] = h;
  swhlo[(size_t)n * 64 + lane] = l;
}

// ---------------- fused GRU (MFMA + LDS gate exchange) ----------------

template <int USE_H, int WRITE_SPLIT>
__global__ __launch_bounds__(256) void gru_kernel(
    const unsigned short* __restrict__ xhi, const unsigned short* __restrict__ xlo,
    const unsigned short* __restrict__ hhi, const unsigned short* __restrict__ hlo,
    const float* __restrict__ hprev,
    const unsigned short* __restrict__ wfi, const unsigned short* __restrict__ wfh,
    const float* __restrict__ b_ih, const float* __restrict__ b_hh,
    float* __restrict__ hout, unsigned short* __restrict__ houthi,
    unsigned short* __restrict__ houtlo, int N, int NT) {
  __shared__ float gi[16][204];
  __shared__ float gh[16][204];
  __shared__ float bias[2][192];
  for (int i = threadIdx.x; i < 192; i += 256) {
    bias[0][i] = b_ih[i];
    bias[1][i] = b_hh[i];
  }
  int lane = threadIdx.x & 63;
  int w = threadIdx.x >> 6;
  bf16x8 bih[3][2], bil[3][2], bhh[3][2], bhl[3][2];
  {
    const short8* fih = (const short8*)wfi;
    const short8* fil = (const short8*)(wfi + 12288);
    const short8* fhh = (const short8*)wfh;
    const short8* fhl = (const short8*)(wfh + 12288);
#pragma unroll
    for (int ct = 0; ct < 3; ++ct)
#pragma unroll
      for (int ks = 0; ks < 2; ++ks) {
        int tci = w * 3 + ct;
        bih[ct][ks] = __builtin_bit_cast(bf16x8, fih[(tci * 2 + ks) * 64 + lane]);
        bil[ct][ks] = __builtin_bit_cast(bf16x8, fil[(tci * 2 + ks) * 64 + lane]);
        if (USE_H) {
          bhh[ct][ks] = __builtin_bit_cast(bf16x8, fhh[(tci * 2 + ks) * 64 + lane]);
          bhl[ct][ks] = __builtin_bit_cast(bf16x8, fhl[(tci * 2 + ks) * 64 + lane]);
        }
      }
  }
  __syncthreads();
  int r15 = lane & 15, kq = lane >> 4;
  int tnode = threadIdx.x >> 4;
  int c4 = (threadIdx.x & 15) * 4;

  for (int nt = blockIdx.x; nt < NT; nt += gridDim.x) {
    int n0 = nt * 16;
    int row = n0 + r15;
    if (row >= N) row = N - 1;
    bf16x8 axh[2], axl[2], ahh2[2], ahl2[2];
    {
      const short8* ax0 = (const short8*)(xhi + (((size_t)row) << 6) + (kq << 3));
      const short8* ax1 = (const short8*)(xlo + (((size_t)row) << 6) + (kq << 3));
      axh[0] = __builtin_bit_cast(bf16x8, ax0[0]);
      axh[1] = __builtin_bit_cast(bf16x8, ax0[4]);
      axl[0] = __builtin_bit_cast(bf16x8, ax1[0]);
      axl[1] = __builtin_bit_cast(bf16x8, ax1[4]);
      if (USE_H) {
        const short8* ah0 = (const short8*)(hhi + (((size_t)row) << 6) + (kq << 3));
        const short8* ah1 = (const short8*)(hlo + (((size_t)row) << 6) + (kq << 3));
        ahh2[0] = __builtin_bit_cast(bf16x8, ah0[0]);
        ahh2[1] = __builtin_bit_cast(bf16x8, ah0[4]);
        ahl2[0] = __builtin_bit_cast(bf16x8, ah1[0]);
        ahl2[1] = __builtin_bit_cast(bf16x8, ah1[4]);
      }
    }
#pragma unroll
    for (int ct = 0; ct < 3; ++ct) {
      f32x4 ax = {0.f, 0.f, 0.f, 0.f};
      f32x4 ah = {0.f, 0.f, 0.f, 0.f};
#pragma unroll
      for (int ks = 0; ks < 2; ++ks) {
        ax = MFMA16(axh[ks], bih[ct][ks], ax);
        ax = MFMA16(axh[ks], bil[ct][ks], ax);
        ax = MFMA16(axl[ks], bih[ct][ks], ax);
        if (USE_H) {
          ah = MFMA16(ahh2[ks], bhh[ct][ks], ah);
          ah = MFMA16(ahh2[ks], bhl[ct][ks], ah);
          ah = MFMA16(ahl2[ks], bhh[ct][ks], ah);
        }
      }
      int c = (w * 3 + ct) * 16 + r15;
#pragma unroll
      for (int reg = 0; reg < 4; ++reg) {
        gi[(kq << 2) + reg][c] = ax[reg];
        if (USE_H) gh[(kq << 2) + reg][c] = ah[reg];
      }
    }
    __syncthreads();
    int n = n0 + tnode;
    if (n < N) {
      float4 hp;
      if (USE_H) hp = *(const float4*)(hprev + (((size_t)n) << 6) + c4);
      else hp = make_float4(0.f, 0.f, 0.f, 0.f);
      float hpv[4] = {hp.x, hp.y, hp.z, hp.w};
      float ov[4];
      ushort4 oh, ol;
      unsigned short* ohp = &oh.x;
      unsigned short* olp = &ol.x;
#pragma unroll
      for (int i = 0; i < 4; ++i) {
        int c = c4 + i;
        float gir = gi[tnode][c] + bias[0][c];
        float giz = gi[tnode][c + 64] + bias[0][c + 64];
        float gin = gi[tnode][c + 128] + bias[0][c + 128];
        float ghr = (USE_H ? gh[tnode][c] : 0.f) + bias[1][c];
        float ghz = (USE_H ? gh[tnode][c + 64] : 0.f) + bias[1][c + 64];
        float ghn = (USE_H ? gh[tnode][c + 128] : 0.f) + bias[1][c + 128];
        float r = 1.f / (1.f + __expf(-(gir + ghr)));
        float z = 1.f / (1.f + __expf(-(giz + ghz)));
        float nn = tanhf(gin + r * ghn);
        float o = (1.f - z) * nn + z * hpv[i];
        ov[i] = o;
        if (WRITE_SPLIT) split2(o, &ohp[i], &olp[i]);
      }
      *(float4*)(hout + (((size_t)n) << 6) + c4) = make_float4(ov[0], ov[1], ov[2], ov[3]);
      if (WRITE_SPLIT) {
        *(ushort4*)(houthi + (((size_t)n) << 6) + c4) = oh;
        *(ushort4*)(houtlo + (((size_t)n) << 6) + c4) = ol;
      }
    }
    __syncthreads();
  }
}

// ---------------- batchnorm ----------------

__global__ __launch_bounds__(256) void bn_stats_kernel(
    const float* __restrict__ h, float* __restrict__ stats, int N) {
  int tid = threadIdx.x;
  int c = tid & 63;
  float s = 0.f, ss = 0.f;
  for (int n = blockIdx.x * 4 + (tid >> 6); n < N; n += gridDim.x * 4) {
    float v = h[(size_t)n * 64 + c];
    s += v;
    ss += v * v;
  }
  __shared__ float sm[2][256];
  sm[0][tid] = s;
  sm[1][tid] = ss;
  __syncthreads();
  if (tid < 64) {
    s = sm[0][tid] + sm[0][tid + 64] + sm[0][tid + 128] + sm[0][tid + 192];
    ss = sm[1][tid] + sm[1][tid + 64] + sm[1][tid + 128] + sm[1][tid + 192];
    atomicAdd(&stats[tid], s);
    atomicAdd(&stats[64 + tid], ss);
  }
}

__global__ __launch_bounds__(256) void bn_apply_kernel(
    float* out, const float* __restrict__ stats,
    const float* __restrict__ gamma, const float* __restrict__ beta,
    int N, int total) {
  int idx = blockIdx.x * 256 + threadIdx.x;
  if (idx >= total) return;
  int c = idx & 63;
  float invN = 1.f / (float)N;
  float mean = stats[c] * invN;
  float var = stats[64 + c] * invN - mean * mean;
  float sc = rsqrtf(var + 1e-5f) * gamma[c];
  float sh = beta[c] - mean * sc;
  out[idx] = out[idx] * sc + sh;
}

// ---------------- launch ----------------

extern "C" void kernel_launch(void* const* d_in, const int* in_sizes, int n_in,
                              void* d_out, int out_size, void* d_ws, size_t ws_size,
                              hipStream_t stream) {
  const float* h     = (const float*)d_in[0];
  const float* norm  = (const float*)d_in[1];
  const float* W     = (const float*)d_in[2];
  const float* w_ih  = (const float*)d_in[3];
  const float* w_hh  = (const float*)d_in[4];
  const float* b_ih  = (const float*)d_in[5];
  const float* b_hh  = (const float*)d_in[6];
  const float* gamma = (const float*)d_in[7];
  const float* beta  = (const float*)d_in[8];
  const int* src     = (const int*)d_in[9];
  const int* dst     = (const int*)d_in[10];
  const int* rel     = (const int*)d_in[11];
  float* out = (float*)d_out;

  const int N = in_sizes[0] / 64;
  const int E = in_sizes[1];
  const int NT = (N + 15) / 16;

  char* wsp = (char*)d_ws;
  float* t = (float*)wsp;              wsp += (size_t)3 * N * 64 * 4;
  unsigned short* xhi = (unsigned short*)wsp; wsp += (size_t)N * 64 * 2;
  unsigned short* xlo = (unsigned short*)wsp; wsp += (size_t)N * 64 * 2;
  unsigned short* swhhi = (unsigned short*)wsp; wsp += (size_t)N * 64 * 2;
  unsigned short* swhlo = (unsigned short*)wsp; wsp += (size_t)N * 64 * 2;
  unsigned short* frags = (unsigned short*)wsp; wsp += 6 * 12288 * 2;
  unsigned* offs = (unsigned*)wsp;   wsp += ((size_t)N + 4) * 4;
  unsigned* cursor = (unsigned*)wsp; wsp += (size_t)N * 4;
  uint2* epack = (uint2*)wsp;        wsp += (size_t)E * 8;
  unsigned* bsums = (unsigned*)wsp;  wsp += 128 * 4;
  float* stats = (float*)wsp;        wsp += 128 * 4;

  const unsigned short* frag_t = frags;
  const unsigned short* frag_i = frags + 2 * 12288;
  const unsigned short* frag_h = frags + 4 * 12288;

  const int M = (N + 1023) / 1024;

  hipMemsetAsync(cursor, 0, (size_t)N * 4, stream);
  hipMemsetAsync(stats, 0, 128 * 4, stream);

  wprep_kernel<<<18, 256, 0, stream>>>(W, w_ih, w_hh, frags);
  conv_split_kernel<<<(N * 16 + 255) / 256, 256, 0, stream>>>(h, xhi, xlo, N * 16);

  // CSR over dst (graph is layer-invariant)
  count_kernel<<<(E / 4 + 255) / 256, 256, 0, stream>>>(dst, cursor, E);
  scan_k1<<<M, 1024, 0, stream>>>(cursor, offs, bsums, N);
  scan_k2<<<1, 128, 0, stream>>>(bsums, offs, M, N);
  scan_k3<<<(N + 255) / 256, 256, 0, stream>>>(offs, bsums, cursor, N);
  fill_kernel<<<(E + 255) / 256, 256, 0, stream>>>(src, dst, rel, norm, cursor,
                                                   epack, E);

  // layer 0 (hstate = 0): gru writes h1 fp32 -> out, h1 split -> xhi/xlo
  transform_kernel<<<1024, 256, 0, stream>>>(xhi, xlo, frag_t, t, N, NT);
  gather_kernel<<<(N + 3) / 4, 256, 0, stream>>>(t, offs, epack, swhhi, swhlo, N);
  gru_kernel<0, 1><<<1024, 256, 0, stream>>>(swhhi, swhlo, nullptr, nullptr, nullptr,
                                             frag_i, frag_h, b_ih, b_hh,
                                             out, xhi, xlo, N, NT);

  // layer 1: transform reads h1 split; gru h-path reads h1 split, hprev = out
  transform_kernel<<<1024, 256, 0, stream>>>(xhi, xlo, frag_t, t, N, NT);
  gather_kernel<<<(N + 3) / 4, 256, 0, stream>>>(t, offs, epack, swhhi, swhlo, N);
  gru_kernel<1, 0><<<1024, 256, 0, stream>>>(swhhi, swhlo, xhi, xlo, out,
                                             frag_i, frag_h, b_ih, b_hh,
                                             out, nullptr, nullptr, N, NT);

  bn_stats_kernel<<<256, 256, 0, stream>>>(out, stats, N);
  int total = N * 64;
  bn_apply_kernel<<<(total + 255) / 256, 256, 0, stream>>>(out, stats, gamma,
                                                           beta, N, total);
}